// Round 6
// baseline (516.477 us; speedup 1.0000x reference)
//
#include <hip/hip_runtime.h>
#include <hip/hip_bf16.h>

// ---------------------------------------------------------------------------
// QLenet forward, exact-math strategy:
//   All fq() outputs are e5m2 grid values (<=3 significant bits). Products of
//   two grid values have <=6-bit mantissas; dot sums (<=400 terms, bounded
//   exponent span) are EXACT in f64 -> order-independent -> matches float64
//   numpy reference. Intermediates stored as bf16 (exact for grid values);
//   LDS tiles hold f32 (also exact), accumulation stays f64.
// Round 16 -> 17:
//   * r16 falsified the weight-scatter theory: coalescing weight staging
//     left FETCH/WRITE identical (404/165 MB). Decomposition: FETCH =
//     13.1M stores x 32B = one RMW-fetch PER 2-byte c2 store. At 44%
//     occupancy the L2 evicts dirty sectors between consecutive scalar
//     stores (r13/r14 at ~1 block/CU merged them; 9.5/27 MB).
//   * Fix: LDS-bounce epilogue. Each wave assembles its 16x16 bf16 tile in
//     LDS (probed row/col), then stores it as ONE coalesced 512B wave store
//     (c2 tile = (b0*100+16t)*16 .. +256 ushorts is contiguous). No
//     sub-line stores remain -> RMW mechanism gone at any occupancy.
// ---------------------------------------------------------------------------

#define BATCH 8192

typedef double d4 __attribute__((ext_vector_type(4)));

// fq on f64: round to FP(e5m2) nearest-even, subnormal granule 2^-16,
// clip +-57344. Integer RNE on the mantissa; carry propagates into exponent.
__device__ __forceinline__ double fq_d(double x) {
    long long b = __double_as_longlong(x);
    long long ab = b & 0x7fffffffffffffffLL;
    if (ab == 0) return x;                       // +-0 preserved
    double q;
    if (ab >= 0x3F10000000000000LL) {            // |x| >= 2^-14
        long long r = b + 0x0001FFFFFFFFFFFFLL + ((b >> 50) & 1LL);
        r &= 0xFFFC000000000000LL;
        q = __longlong_as_double(r);
        q = fmin(fmax(q, -57344.0), 57344.0);
    } else {                                     // subnormal grid: 2^-16
        q = rint(x * 65536.0) * 1.52587890625e-05;
    }
    return q;
}

// fq on f32 input values (exact f32 -> same e5m2 result as the f64 path).
__device__ __forceinline__ float fq_f(float x) {
    int b = __float_as_int(x);
    int ab = b & 0x7fffffff;
    if (ab == 0) return x;
    float q;
    if (ab >= 0x38800000) {                      // |x| >= 2^-14
        int r = b + 0x000FFFFF + ((b >> 21) & 1);
        r &= 0xFFE00000;                         // sign+exp+2 mantissa bits
        q = __int_as_float(r);
        q = fminf(fmaxf(q, -57344.0f), 57344.0f);
    } else {
        q = rintf(x * 65536.0f) * 1.52587890625e-05f;
    }
    return q;
}

__device__ __forceinline__ unsigned short bfbits(double q) {
    __hip_bfloat16 h = __float2bfloat16((float)q);   // exact for grid values
    return *(unsigned short*)&h;
}

__device__ __forceinline__ float bfval(unsigned short u) {
    return __bfloat162float(*(__hip_bfloat16*)&u);
}

// patch offset for flat k in [0,152): k = ci*25 + u*5 + v -> ci*196+u*14+v.
// Exact magic-div (verified for all k<=151); pad k>=150 handled by caller.
__device__ __forceinline__ int patch_off(int k) {
    int ci = (k * 1311) >> 15;      // k/25, exact for k<=151
    int rem = k - 25 * ci;
    int u = (rem * 13) >> 6;        // rem/5, exact for rem<25
    int v = rem - 5 * u;
    return ci * 196 + u * 14 + v;
}

// ---------------- merged prep (all f32-path fq) ----------------
// qw2t: conv2 weights pre-transposed to [152][16] f32 (k-major, zero-padded)
// so kconv2's LDS staging is a pure coalesced copy.
__global__ void kprep(const float* __restrict__ w1, const float* __restrict__ w2,
                      const float* __restrict__ fb1, const float* __restrict__ fb2,
                      const float* __restrict__ fb3, const float* __restrict__ fw1,
                      const float* __restrict__ fw2, const float* __restrict__ fw3,
                      float* __restrict__ qw1, float* __restrict__ qw2t,
                      float* __restrict__ qfb1, float* __restrict__ qfb2,
                      float* __restrict__ qfb3, float* __restrict__ Wt1,
                      float* __restrict__ Wt2, float* __restrict__ Wt3) {
    int i = blockIdx.x * 256 + threadIdx.x;
    if (i < 150) { qw1[i] = fq_f(w1[i]); return; }
    i -= 150;
    if (i < 2432) { int k = i >> 4, co = i & 15;
        qw2t[i] = (k < 150) ? fq_f(w2[co * 150 + k]) : 0.0f; return; }
    i -= 2432;
    if (i < 120) { qfb1[i] = fq_f(fb1[i]); return; }
    i -= 120;
    if (i < 84) { qfb2[i] = fq_f(fb2[i]); return; }
    i -= 84;
    if (i < 10) { qfb3[i] = fq_f(fb3[i]); return; }
    i -= 10;
    if (i < 51200) { int k = i / 128, o = i % 128;
        Wt1[i] = (o < 120) ? fq_f(fw1[o * 400 + k]) : 0.0f; return; }
    i -= 51200;
    if (i < 15360) { int k = i / 128, o = i % 128;
        Wt2[i] = (o < 84) ? fq_f(fw2[o * 120 + k]) : 0.0f; return; }
    i -= 15360;
    if (i < 1344) { int k = i / 16, o = i % 16;
        Wt3[i] = (o < 10) ? fq_f(fw3[o * 84 + k]) : 0.0f; return; }
}
#define PREP_TOTAL (150 + 2432 + 120 + 84 + 10 + 51200 + 15360 + 1344)

// ---------------- conv1 + fq + fused BN stats (r9 version) ----------------
// [B,1,32,32] -> [B,6,28,28]. 3 images/block; task = 2x7 output tile with
// rotated-w row reuse. x tile f32 (fq_f staging), stride 33.
__global__ __launch_bounds__(256) void kconv1(const float* __restrict__ x,
        const float* __restrict__ qw, __hip_bfloat16* __restrict__ c1,
        int nimg_total, double* __restrict__ st1) {
    __shared__ float sxf[3 * 1056];   // 3 x (32 rows x 33) f32
    __shared__ double swd[152];
    __shared__ double sred[6][2];
    int t = threadIdx.x;
    int b0 = blockIdx.x * 3;
    int nimg = nimg_total - b0; if (nimg > 3) nimg = 3;
    for (int i = t; i < nimg * 1024; i += 256) {
        int img = i >> 10, idx = i & 1023;
        sxf[img * 1056 + (idx >> 5) * 33 + (idx & 31)] =
            fq_f(x[(size_t)(b0 + img) * 1024 + idx]);
    }
    if (t < 150) swd[t] = (double)qw[t];
    if (t >= 192 && t < 204) ((double*)sred)[t - 192] = 0.0;
    __syncthreads();
    int ntask = nimg * 336;           // 6 co x 14 rowpairs x 4 colchunks
    for (int task = t; task < ntask; task += 256) {
        int img = task / 336; int rr = task % 336;
        int co = rr / 56; int rem = rr % 56;
        int i0 = (rem >> 2) * 2;      // 0,2,...,26
        int j0 = (rem & 3) * 7;       // 0,7,14,21
        const double* wp = &swd[co * 25];
        double a0[7], a1[7];
        #pragma unroll
        for (int j = 0; j < 7; ++j) { a0[j] = 0.0; a1[j] = 0.0; }
        double wr[5], wq[5];
        #pragma unroll
        for (int u = 0; u < 6; ++u) {
            const float* xr = &sxf[img * 1056 + (i0 + u) * 33 + j0];
            double xv[11];
            #pragma unroll
            for (int k = 0; k < 11; ++k) xv[k] = (double)xr[k];
            if (u < 5) {
                #pragma unroll
                for (int tt = 0; tt < 5; ++tt) wr[tt] = wp[u * 5 + tt];
                #pragma unroll
                for (int j = 0; j < 7; ++j)
                    a0[j] = fma(xv[j], wr[0], fma(xv[j+1], wr[1], fma(xv[j+2], wr[2],
                            fma(xv[j+3], wr[3], fma(xv[j+4], wr[4], a0[j])))));
            }
            if (u >= 1) {
                #pragma unroll
                for (int j = 0; j < 7; ++j)
                    a1[j] = fma(xv[j], wq[0], fma(xv[j+1], wq[1], fma(xv[j+2], wq[2],
                            fma(xv[j+3], wq[3], fma(xv[j+4], wq[4], a1[j])))));
            }
            #pragma unroll
            for (int tt = 0; tt < 5; ++tt) wq[tt] = wr[tt];   // SSA rotate
        }
        size_t base = ((size_t)(b0 + img) * 6 + co) * 784 + (size_t)i0 * 28 + j0;
        double s = 0.0, s2 = 0.0;
        #pragma unroll
        for (int j = 0; j < 7; ++j) {
            double q0 = fq_d(a0[j]), q1 = fq_d(a1[j]);
            ((unsigned short*)c1)[base + j]      = bfbits(q0);
            ((unsigned short*)c1)[base + 28 + j] = bfbits(q1);
            s += q0 + q1; s2 += q0 * q0 + q1 * q1;
        }
        atomicAdd(&sred[co][0], s);
        atomicAdd(&sred[co][1], s2);
    }
    __syncthreads();
    if (t < 12) atomicAdd(&st1[t * 32 + (blockIdx.x & 31)], ((double*)sred)[t]);
}

// ---------------- finalize BN1 from 32-binned stats ----------------
__global__ void kfinal(const double* __restrict__ st, double* __restrict__ mr,
                       int C, double N) {
    int c = threadIdx.x;
    if (c < C) {
        double s = 0.0, s2 = 0.0;
        for (int b = 0; b < 32; ++b) { s += st[c * 64 + b]; s2 += st[c * 64 + 32 + b]; }
        double m = s / N;
        double v = s2 / N - m * m;
        mr[2 * c] = m;
        mr[2 * c + 1] = 1.0 / sqrt(v + 1e-5);
    }
}

// ---------------- bn1 + fq + relu + 2x2 pool (monotone single-fq) ----------
__global__ __launch_bounds__(256) void kpool1(const __hip_bfloat16* __restrict__ c1,
        const double* __restrict__ mr1, const float* __restrict__ g1,
        const float* __restrict__ be1, __hip_bfloat16* __restrict__ p1) {
    int idx = blockIdx.x * 256 + threadIdx.x;   // pair-task: B*6*14*7
    int pp = idx % 7;  int t1 = idx / 7;
    int ph = t1 % 14;  int t2 = t1 / 14;
    int c  = t2 % 6;   int b  = t2 / 6;
    double m = mr1[2 * c], r = mr1[2 * c + 1];
    double gg = (double)g1[c], bb = (double)be1[c];
    bool useMax = (r * gg) >= 0.0;              // selection only
    const __hip_bfloat16* src = c1 + (((size_t)b * 6 + c) * 28 + 2 * ph) * 28 + 4 * pp;
    ushort4 u0 = *(const ushort4*)src;
    ushort4 u1 = *(const ushort4*)(src + 28);
    float f0 = bfval(u0.x), f1 = bfval(u0.y);
    float f2 = bfval(u0.z), f3 = bfval(u0.w);
    float f4 = bfval(u1.x), f5 = bfval(u1.y);
    float f6 = bfval(u1.z), f7 = bfval(u1.w);
    float va = useMax ? fmaxf(fmaxf(f0, f1), fmaxf(f4, f5))
                      : fminf(fminf(f0, f1), fminf(f4, f5));
    float vb = useMax ? fmaxf(fmaxf(f2, f3), fmaxf(f6, f7))
                      : fminf(fminf(f2, f3), fminf(f6, f7));
    double qa = fq_d((((double)va - m) * r) * gg + bb);
    double qb = fq_d((((double)vb - m) * r) * gg + bb);
    qa = fmax(qa, 0.0); qb = fmax(qb, 0.0);
    ushort2 pk; pk.x = bfbits(qa); pk.y = bfbits(qb);
    *(ushort2*)&p1[((size_t)b * 6 + c) * 196 + ph * 14 + 2 * pp] = pk;
}

// ---------------- conv2 as implicit GEMM on v_mfma_f64_16x16x4_f64 --------
// [B,6,14,14] -> [B,100,16] (position-major output). 4 images/block,
// 256 thr = 4 waves, grid 2048. M = 400 positions (25 exact 16-tiles),
// N = 16 co, K = 152 (150 + 2 pad).
// k-slot remap: MFMA m (0..37) pairs lane-group c with k = m + 38c
// (contiguous per lane; A/B use the same grouping so the exact sum is
// invariant — r13-verified). Offsets pure arithmetic (magic-div), B address
// linear in m. 2 chains/tile. Weights staged coalesced from qw2t (r16).
// D-side (reg,lane)->(row,col) mapping PROBED at runtime (r13-verified).
// r17: epilogue bounces each 16x16 tile through LDS and issues ONE
// coalesced 512B wave store (c2 tile region is contiguous) — kills the
// per-2B-store HBM RMW that made r15/r16 memory-bound.
__global__ __launch_bounds__(256, 4) void kconv2(const __hip_bfloat16* __restrict__ p1,
        const float* __restrict__ qw2t, __hip_bfloat16* __restrict__ c2,
        double* __restrict__ st2) {
    __shared__ float sxf[4704];        // 4 x [6][14][14] f32 (exact grid vals)
    __shared__ float swf[2432];        // [152][16] f32 weights, k-major (exact)
    __shared__ unsigned short sep[4][256];  // per-wave 16x16 bf16 out tile
    __shared__ double sred[16][2];
    int t = threadIdx.x;
    int b0 = blockIdx.x * 4;
    // stage x: 4704 bf16 -> f32, vectorized ushort4
    const ushort4* srcp = (const ushort4*)(p1 + (size_t)b0 * 1176);
    for (int i = t; i < 1176; i += 256) {
        ushort4 u = srcp[i];
        float* d = &sxf[4 * i];
        d[0] = bfval(u.x);
        d[1] = bfval(u.y);
        d[2] = bfval(u.z);
        d[3] = bfval(u.w);
    }
    // stage weights: pure coalesced copy (608 x float4, L2-resident)
    {
        const float4* wsrc = (const float4*)qw2t;
        float4* wdst = (float4*)swf;
        for (int i = t; i < 608; i += 256) wdst[i] = wsrc[i];
    }
    if (t < 32) ((double*)sred)[t] = 0.0;
    __syncthreads();

    int l = t & 63, w = t >> 6;        // lane, wave
    int c = l >> 4, r16 = l & 15;      // k-group / {A-row,B-col} staging index

    // ---- layout probes (exact small-int arithmetic, 2 MFMAs) ----
    d4 pz = {0.0, 0.0, 0.0, 0.0};
    d4 prow = __builtin_amdgcn_mfma_f64_16x16x4f64((double)r16, 0.25, pz, 0, 0, 0);
    d4 pcol = __builtin_amdgcn_mfma_f64_16x16x4f64(1.0, 0.25 * (double)r16, pz, 0, 0, 0);
    int rowidx[4], colidx[4];
    #pragma unroll
    for (int j = 0; j < 4; ++j) { rowidx[j] = (int)prow[j]; colidx[j] = (int)pcol[j]; }

    int kbase = 38 * c;                // lane's contiguous k-range start
    unsigned short* myep = sep[w];
    double ls = 0.0, ls2 = 0.0;        // per-lane stats (col fixed per lane)
    int co0 = colidx[0];
    for (int tile = w; tile < 25; tile += 4) {
        int pos = tile * 16 + r16;     // A-row (staging) for this lane
        int abase = (pos / 100) * 1176 + ((pos % 100) / 10) * 14 + (pos % 10);
        d4 a0 = {0.0, 0.0, 0.0, 0.0}, a1 = {0.0, 0.0, 0.0, 0.0};
        #pragma unroll
        for (int s = 0; s < 19; ++s) {
            int k0 = kbase + s;        // chain 0: m = s
            int k1 = kbase + s + 19;   // chain 1: m = s + 19
            int i0 = abase + patch_off(k0);
            int i1 = abase + patch_off(k1);
            // pad slots (k>=150, only c=3) map OOB; clamp to any in-range
            // address — their B weight is exactly 0, so finite*0 = 0.
            if (i0 > 4703) i0 = 0;
            if (i1 > 4703) i1 = 0;
            double x0 = (double)sxf[i0];
            double x1 = (double)sxf[i1];
            double w0 = (double)swf[k0 * 16 + r16];
            double w1 = (double)swf[k1 * 16 + r16];
            a0 = __builtin_amdgcn_mfma_f64_16x16x4f64(x0, w0, a0, 0, 0, 0);
            a1 = __builtin_amdgcn_mfma_f64_16x16x4f64(x1, w1, a1, 0, 0, 0);
        }
        // epilogue: fq + stats; assemble tile in LDS (probed mapping), then
        // ONE coalesced 512B wave store (c2 flat idx = (b0*100+pos)*16+col
        // -> tile region [(b0*100+16*tile)*16, +256) ushorts, contiguous).
        #pragma unroll
        for (int j = 0; j < 4; ++j) {
            double q = fq_d(a0[j] + a1[j]);
            myep[rowidx[j] * 16 + colidx[j]] = bfbits(q);
            ls += q; ls2 += q * q;
        }
        ushort4 v = *(const ushort4*)&myep[l * 4];   // wave-internal, in-order
        *(ushort4*)((unsigned short*)c2 + ((size_t)b0 * 100 + tile * 16) * 16 + l * 4) = v;
    }
    atomicAdd(&sred[co0][0], ls);
    atomicAdd(&sred[co0][1], ls2);
    __syncthreads();
    if (t < 32) atomicAdd(&st2[t * 32 + (blockIdx.x & 31)], ((double*)sred)[t]);
}

// ---------------- fc1: fused bn2-finalize + bn2/fq/relu/pool staging -------
// BT=8 (1024 blocks): c2 [B,100,16] position-major. Pool reads global
// directly with c-fastest map: 16 consecutive channels per 16-thread
// cluster -> 32B-contiguous loads. LDS 25.9KB -> 6 blocks/CU.
__global__ __launch_bounds__(256) void kfc1(const __hip_bfloat16* __restrict__ c2,
        const double* __restrict__ st2, const float* __restrict__ g2,
        const float* __restrict__ be2, const float* __restrict__ Wt,
        const float* __restrict__ qb, __hip_bfloat16* __restrict__ outb) {
    constexpr int IN = 400, OUT = 120, OUTP = 128, ROWS = 4, BT = 8;
    __shared__ double sx[BT][IN];
    __shared__ double sbn[16][4];
    int t = threadIdx.x;
    int b0 = blockIdx.x * BT;
    if (t < 16) {                       // inline bn2 finalize from stat bins
        double s = 0.0, s2 = 0.0;
        for (int b = 0; b < 32; ++b) { s += st2[t * 64 + b]; s2 += st2[t * 64 + 32 + b]; }
        double m = s / (819200.0);      // 8192*100
        double v = s2 / (819200.0) - m * m;
        sbn[t][0] = m; sbn[t][1] = 1.0 / sqrt(v + 1e-5);
        sbn[t][2] = (double)g2[t]; sbn[t][3] = (double)be2[t];
    }
    __syncthreads();
    for (int i = t; i < BT * IN; i += 256) {
        int cc = i & 15;                // channel fastest (coalesced)
        int rem = (i >> 4) % 25;        // pooled position
        int r = i / 400;                // image row within tile
        int ph = rem / 5, pw = rem % 5;
        const __hip_bfloat16* src = c2 + ((size_t)(b0 + r) * 100 + 20 * ph + 2 * pw) * 16 + cc;
        double m = sbn[cc][0], rr = sbn[cc][1], gg = sbn[cc][2], bb = sbn[cc][3];
        float f0 = __bfloat162float(src[0]),   f1 = __bfloat162float(src[16]);
        float f2 = __bfloat162float(src[160]), f3 = __bfloat162float(src[176]);
        bool useMax = (rr * gg) >= 0.0;
        float v = useMax ? fmaxf(fmaxf(f0, f1), fmaxf(f2, f3))
                         : fminf(fminf(f0, f1), fminf(f2, f3));
        double q = fq_d((((double)v - m) * rr) * gg + bb);
        sx[r][cc * 25 + rem] = fmax(q, 0.0);
    }
    __syncthreads();
    int o = t % OUTP;
    int g = t / OUTP;
    double acc[ROWS];
    double bias = (o < OUT) ? (double)qb[o] : 0.0;
    #pragma unroll
    for (int r = 0; r < ROWS; ++r) acc[r] = bias;
    #pragma unroll 4
    for (int k = 0; k < IN; ++k) {
        double w = (double)Wt[k * OUTP + o];   // coalesced, L2-resident
        #pragma unroll
        for (int r = 0; r < ROWS; ++r)
            acc[r] = fma(sx[g * ROWS + r][k], w, acc[r]);
    }
    if (o < OUT) {
        #pragma unroll
        for (int r = 0; r < ROWS; ++r) {
            double q = fq_d(acc[r]);
            if (q < 0.0) q = 0.0;
            outb[(size_t)(b0 + g * ROWS + r) * OUT + o] = __float2bfloat16((float)q);
        }
    }
}

// ---------------- fused fc2+fc3: a1 [B,120] -> out [B,10] ----------------
__global__ __launch_bounds__(256) void kfc23(const __hip_bfloat16* __restrict__ a1,
        const float* __restrict__ Wt2, const float* __restrict__ qfb2,
        const float* __restrict__ Wt3, const float* __restrict__ qfb3,
        float* __restrict__ out) {
    __shared__ double sx1[16][120];
    __shared__ double s2[16][84];
    int t = threadIdx.x;
    int b0 = blockIdx.x * 16;
    for (int i = t; i < 16 * 120; i += 256) {
        int r = i / 120, k = i % 120;
        sx1[r][k] = (double)__bfloat162float(a1[(size_t)(b0 + r) * 120 + k]);
    }
    __syncthreads();
    {   // fc2: 2 groups x 8 rows x 128 output lanes
        int o = t % 128, g = t / 128;
        double acc[8];
        double bias = (o < 84) ? (double)qfb2[o] : 0.0;
        #pragma unroll
        for (int r = 0; r < 8; ++r) acc[r] = bias;
        #pragma unroll 4
        for (int k = 0; k < 120; ++k) {
            double w = (double)Wt2[k * 128 + o];
            #pragma unroll
            for (int r = 0; r < 8; ++r)
                acc[r] = fma(sx1[g * 8 + r][k], w, acc[r]);
        }
        if (o < 84) {
            #pragma unroll
            for (int r = 0; r < 8; ++r) {
                double q = fq_d(acc[r]);
                s2[g * 8 + r][o] = fmax(q, 0.0);
            }
        }
    }
    __syncthreads();
    {   // fc3: 16 rows x 16 output lanes (10 used)
        int o = t % 16, g = t / 16;
        double acc = (o < 10) ? (double)qfb3[o] : 0.0;
        #pragma unroll 4
        for (int k = 0; k < 84; ++k)
            acc = fma(s2[g][k], (double)Wt3[k * 16 + o], acc);
        if (o < 10)
            out[(size_t)(b0 + g) * 10 + o] = (float)fq_d(acc);
    }
}

// ---------------------------------------------------------------------------
extern "C" void kernel_launch(void* const* d_in, const int* in_sizes, int n_in,
                              void* d_out, int out_size, void* d_ws, size_t ws_size,
                              hipStream_t stream) {
    const float* x   = (const float*)d_in[0];
    const float* w1  = (const float*)d_in[1];
    const float* g1  = (const float*)d_in[2];
    const float* be1 = (const float*)d_in[3];
    const float* w2  = (const float*)d_in[4];
    const float* g2  = (const float*)d_in[5];
    const float* be2 = (const float*)d_in[6];
    const float* fw1 = (const float*)d_in[7];
    const float* fb1 = (const float*)d_in[8];
    const float* fw2 = (const float*)d_in[9];
    const float* fb2 = (const float*)d_in[10];
    const float* fw3 = (const float*)d_in[11];
    const float* fb3 = (const float*)d_in[12];

    char* ws = (char*)d_ws;
    double* stats1 = (double*)(ws + 0);      // [6][2][32] dbl
    double* stats2 = (double*)(ws + 3072);   // [16][2][32] dbl (ends 11264)
    double* mr1    = (double*)(ws + 11264);  // 12 dbl
    float* qw1  = (float*)(ws + 12288);
    float* qw2t = (float*)(ws + 13312);      // [152][16] f32, ends 23040
    float* qfb1 = (float*)(ws + 23040);
    float* qfb2 = (float*)(ws + 23552);
    float* qfb3 = (float*)(ws + 24064);
    float* Wt1  = (float*)(ws + 24576);      // 400*128
    float* Wt2  = (float*)(ws + 229376);     // 120*128
    float* Wt3  = (float*)(ws + 290816);     // 84*16
    __hip_bfloat16* c1 = (__hip_bfloat16*)(ws + 303104);      // [B,6,28,28] 77.1 MB
    __hip_bfloat16* p1 = (__hip_bfloat16*)(ws + 77373440);    // [B,6,14,14] 19.3 MB
    __hip_bfloat16* c2 = (__hip_bfloat16*)(ws + 303104);      // [B,100,16] (c1 dead)
    __hip_bfloat16* a1 = (__hip_bfloat16*)(ws + 303104 + 26214400); // [B,120]

    hipMemsetAsync(ws, 0, 11264, stream);

    kprep<<<(PREP_TOTAL + 255) / 256, 256, 0, stream>>>(
        w1, w2, fb1, fb2, fb3, fw1, fw2, fw3,
        qw1, qw2t, qfb1, qfb2, qfb3, Wt1, Wt2, Wt3);

    // conv1 + fq + stats -> c1   (3 images/block, 2x7 tiles)
    kconv1<<<(BATCH + 2) / 3, 256, 0, stream>>>(x, qw1, c1, BATCH, stats1);
    kfinal<<<1, 32, 0, stream>>>(stats1, mr1, 6, (double)BATCH * 784.0);
    // bn1 + fq + relu + pool -> p1
    kpool1<<<BATCH * 6 * 14 * 7 / 256, 256, 0, stream>>>(c1, mr1, g1, be1, p1);
    // conv2 via f64 MFMA implicit GEMM (coalesced LDS-bounce stores) -> c2
    kconv2<<<BATCH / 4, 256, 0, stream>>>(p1, qw2t, c2, stats2);
    // fc1 (inline bn2 finalize + fused pool staging, +relu) -> a1 [B,120]
    kfc1<<<BATCH / 8, 256, 0, stream>>>(c2, stats2, g2, be2, Wt1, qfb1, a1);
    // fused fc2+fc3 -> d_out [B,10] float
    kfc23<<<BATCH / 16, 256, 0, stream>>>(a1, Wt2, qfb2, Wt3, qfb3, (float*)d_out);
}

// Round 7
// 448.328 us; speedup vs baseline: 1.1520x; 1.1520x over previous
//
#include <hip/hip_runtime.h>
#include <hip/hip_bf16.h>

// ---------------------------------------------------------------------------
// QLenet forward, exact-math strategy:
//   All fq() outputs are e5m2 grid values (<=3 significant bits). Products of
//   two grid values have <=6-bit mantissas; dot sums (<=400 terms, bounded
//   exponent span) are EXACT in f64 -> order-independent -> matches float64
//   numpy reference. Intermediates stored as bf16 (exact for grid values);
//   LDS tiles hold f32 (also exact), accumulation stays f64.
// Round 17 -> 18:
//   * r16/r17 falsified weight-scatter AND store-RMW as the 370-404MB
//     traffic source (coalescing both changed FETCH by <10%). Clean A/B
//     across rounds: identical logical accesses, 1024-block/320-thr/8-img
//     geometry = 9.5/27 MB (r13/r14); 2048-block/256-thr/4-img = ~400/160MB
//     (r15-r17). Traffic follows CONCURRENCY (cross-XCD L2 dirty-line
//     interaction on kpool1-written p1), not access pattern.
//   * r18 = r13 geometry x r17 code: 8 img/320 thr/1024 blocks with ILP-2
//     MFMA chains + arithmetic patch_off + coalesced weights (qw2t) +
//     LDS-bounce 512B stores + probed epilogue. At ~1-2 waves/SIMD the
//     2 chains double r13's 32% MfmaUtil -> predict ~70-90us, FETCH <30MB.
// ---------------------------------------------------------------------------

#define BATCH 8192

typedef double d4 __attribute__((ext_vector_type(4)));

// fq on f64: round to FP(e5m2) nearest-even, subnormal granule 2^-16,
// clip +-57344. Integer RNE on the mantissa; carry propagates into exponent.
__device__ __forceinline__ double fq_d(double x) {
    long long b = __double_as_longlong(x);
    long long ab = b & 0x7fffffffffffffffLL;
    if (ab == 0) return x;                       // +-0 preserved
    double q;
    if (ab >= 0x3F10000000000000LL) {            // |x| >= 2^-14
        long long r = b + 0x0001FFFFFFFFFFFFLL + ((b >> 50) & 1LL);
        r &= 0xFFFC000000000000LL;
        q = __longlong_as_double(r);
        q = fmin(fmax(q, -57344.0), 57344.0);
    } else {                                     // subnormal grid: 2^-16
        q = rint(x * 65536.0) * 1.52587890625e-05;
    }
    return q;
}

// fq on f32 input values (exact f32 -> same e5m2 result as the f64 path).
__device__ __forceinline__ float fq_f(float x) {
    int b = __float_as_int(x);
    int ab = b & 0x7fffffff;
    if (ab == 0) return x;
    float q;
    if (ab >= 0x38800000) {                      // |x| >= 2^-14
        int r = b + 0x000FFFFF + ((b >> 21) & 1);
        r &= 0xFFE00000;                         // sign+exp+2 mantissa bits
        q = __int_as_float(r);
        q = fminf(fmaxf(q, -57344.0f), 57344.0f);
    } else {
        q = rintf(x * 65536.0f) * 1.52587890625e-05f;
    }
    return q;
}

__device__ __forceinline__ unsigned short bfbits(double q) {
    __hip_bfloat16 h = __float2bfloat16((float)q);   // exact for grid values
    return *(unsigned short*)&h;
}

__device__ __forceinline__ float bfval(unsigned short u) {
    return __bfloat162float(*(__hip_bfloat16*)&u);
}

// patch offset for flat k in [0,152): k = ci*25 + u*5 + v -> ci*196+u*14+v.
// Exact magic-div (verified for all k<=151); pad k>=150 handled by caller.
__device__ __forceinline__ int patch_off(int k) {
    int ci = (k * 1311) >> 15;      // k/25, exact for k<=151
    int rem = k - 25 * ci;
    int u = (rem * 13) >> 6;        // rem/5, exact for rem<25
    int v = rem - 5 * u;
    return ci * 196 + u * 14 + v;
}

// ---------------- merged prep (all f32-path fq) ----------------
// qw2t: conv2 weights pre-transposed to [152][16] f32 (k-major, zero-padded)
// so kconv2's LDS staging is a pure coalesced copy.
__global__ void kprep(const float* __restrict__ w1, const float* __restrict__ w2,
                      const float* __restrict__ fb1, const float* __restrict__ fb2,
                      const float* __restrict__ fb3, const float* __restrict__ fw1,
                      const float* __restrict__ fw2, const float* __restrict__ fw3,
                      float* __restrict__ qw1, float* __restrict__ qw2t,
                      float* __restrict__ qfb1, float* __restrict__ qfb2,
                      float* __restrict__ qfb3, float* __restrict__ Wt1,
                      float* __restrict__ Wt2, float* __restrict__ Wt3) {
    int i = blockIdx.x * 256 + threadIdx.x;
    if (i < 150) { qw1[i] = fq_f(w1[i]); return; }
    i -= 150;
    if (i < 2432) { int k = i >> 4, co = i & 15;
        qw2t[i] = (k < 150) ? fq_f(w2[co * 150 + k]) : 0.0f; return; }
    i -= 2432;
    if (i < 120) { qfb1[i] = fq_f(fb1[i]); return; }
    i -= 120;
    if (i < 84) { qfb2[i] = fq_f(fb2[i]); return; }
    i -= 84;
    if (i < 10) { qfb3[i] = fq_f(fb3[i]); return; }
    i -= 10;
    if (i < 51200) { int k = i / 128, o = i % 128;
        Wt1[i] = (o < 120) ? fq_f(fw1[o * 400 + k]) : 0.0f; return; }
    i -= 51200;
    if (i < 15360) { int k = i / 128, o = i % 128;
        Wt2[i] = (o < 84) ? fq_f(fw2[o * 120 + k]) : 0.0f; return; }
    i -= 15360;
    if (i < 1344) { int k = i / 16, o = i % 16;
        Wt3[i] = (o < 10) ? fq_f(fw3[o * 84 + k]) : 0.0f; return; }
}
#define PREP_TOTAL (150 + 2432 + 120 + 84 + 10 + 51200 + 15360 + 1344)

// ---------------- conv1 + fq + fused BN stats (r9 version) ----------------
// [B,1,32,32] -> [B,6,28,28]. 3 images/block; task = 2x7 output tile with
// rotated-w row reuse. x tile f32 (fq_f staging), stride 33.
__global__ __launch_bounds__(256) void kconv1(const float* __restrict__ x,
        const float* __restrict__ qw, __hip_bfloat16* __restrict__ c1,
        int nimg_total, double* __restrict__ st1) {
    __shared__ float sxf[3 * 1056];   // 3 x (32 rows x 33) f32
    __shared__ double swd[152];
    __shared__ double sred[6][2];
    int t = threadIdx.x;
    int b0 = blockIdx.x * 3;
    int nimg = nimg_total - b0; if (nimg > 3) nimg = 3;
    for (int i = t; i < nimg * 1024; i += 256) {
        int img = i >> 10, idx = i & 1023;
        sxf[img * 1056 + (idx >> 5) * 33 + (idx & 31)] =
            fq_f(x[(size_t)(b0 + img) * 1024 + idx]);
    }
    if (t < 150) swd[t] = (double)qw[t];
    if (t >= 192 && t < 204) ((double*)sred)[t - 192] = 0.0;
    __syncthreads();
    int ntask = nimg * 336;           // 6 co x 14 rowpairs x 4 colchunks
    for (int task = t; task < ntask; task += 256) {
        int img = task / 336; int rr = task % 336;
        int co = rr / 56; int rem = rr % 56;
        int i0 = (rem >> 2) * 2;      // 0,2,...,26
        int j0 = (rem & 3) * 7;       // 0,7,14,21
        const double* wp = &swd[co * 25];
        double a0[7], a1[7];
        #pragma unroll
        for (int j = 0; j < 7; ++j) { a0[j] = 0.0; a1[j] = 0.0; }
        double wr[5], wq[5];
        #pragma unroll
        for (int u = 0; u < 6; ++u) {
            const float* xr = &sxf[img * 1056 + (i0 + u) * 33 + j0];
            double xv[11];
            #pragma unroll
            for (int k = 0; k < 11; ++k) xv[k] = (double)xr[k];
            if (u < 5) {
                #pragma unroll
                for (int tt = 0; tt < 5; ++tt) wr[tt] = wp[u * 5 + tt];
                #pragma unroll
                for (int j = 0; j < 7; ++j)
                    a0[j] = fma(xv[j], wr[0], fma(xv[j+1], wr[1], fma(xv[j+2], wr[2],
                            fma(xv[j+3], wr[3], fma(xv[j+4], wr[4], a0[j])))));
            }
            if (u >= 1) {
                #pragma unroll
                for (int j = 0; j < 7; ++j)
                    a1[j] = fma(xv[j], wq[0], fma(xv[j+1], wq[1], fma(xv[j+2], wq[2],
                            fma(xv[j+3], wq[3], fma(xv[j+4], wq[4], a1[j])))));
            }
            #pragma unroll
            for (int tt = 0; tt < 5; ++tt) wq[tt] = wr[tt];   // SSA rotate
        }
        size_t base = ((size_t)(b0 + img) * 6 + co) * 784 + (size_t)i0 * 28 + j0;
        double s = 0.0, s2 = 0.0;
        #pragma unroll
        for (int j = 0; j < 7; ++j) {
            double q0 = fq_d(a0[j]), q1 = fq_d(a1[j]);
            ((unsigned short*)c1)[base + j]      = bfbits(q0);
            ((unsigned short*)c1)[base + 28 + j] = bfbits(q1);
            s += q0 + q1; s2 += q0 * q0 + q1 * q1;
        }
        atomicAdd(&sred[co][0], s);
        atomicAdd(&sred[co][1], s2);
    }
    __syncthreads();
    if (t < 12) atomicAdd(&st1[t * 32 + (blockIdx.x & 31)], ((double*)sred)[t]);
}

// ---------------- finalize BN1 from 32-binned stats ----------------
__global__ void kfinal(const double* __restrict__ st, double* __restrict__ mr,
                       int C, double N) {
    int c = threadIdx.x;
    if (c < C) {
        double s = 0.0, s2 = 0.0;
        for (int b = 0; b < 32; ++b) { s += st[c * 64 + b]; s2 += st[c * 64 + 32 + b]; }
        double m = s / N;
        double v = s2 / N - m * m;
        mr[2 * c] = m;
        mr[2 * c + 1] = 1.0 / sqrt(v + 1e-5);
    }
}

// ---------------- bn1 + fq + relu + 2x2 pool (monotone single-fq) ----------
__global__ __launch_bounds__(256) void kpool1(const __hip_bfloat16* __restrict__ c1,
        const double* __restrict__ mr1, const float* __restrict__ g1,
        const float* __restrict__ be1, __hip_bfloat16* __restrict__ p1) {
    int idx = blockIdx.x * 256 + threadIdx.x;   // pair-task: B*6*14*7
    int pp = idx % 7;  int t1 = idx / 7;
    int ph = t1 % 14;  int t2 = t1 / 14;
    int c  = t2 % 6;   int b  = t2 / 6;
    double m = mr1[2 * c], r = mr1[2 * c + 1];
    double gg = (double)g1[c], bb = (double)be1[c];
    bool useMax = (r * gg) >= 0.0;              // selection only
    const __hip_bfloat16* src = c1 + (((size_t)b * 6 + c) * 28 + 2 * ph) * 28 + 4 * pp;
    ushort4 u0 = *(const ushort4*)src;
    ushort4 u1 = *(const ushort4*)(src + 28);
    float f0 = bfval(u0.x), f1 = bfval(u0.y);
    float f2 = bfval(u0.z), f3 = bfval(u0.w);
    float f4 = bfval(u1.x), f5 = bfval(u1.y);
    float f6 = bfval(u1.z), f7 = bfval(u1.w);
    float va = useMax ? fmaxf(fmaxf(f0, f1), fmaxf(f4, f5))
                      : fminf(fminf(f0, f1), fminf(f4, f5));
    float vb = useMax ? fmaxf(fmaxf(f2, f3), fmaxf(f6, f7))
                      : fminf(fminf(f2, f3), fminf(f6, f7));
    double qa = fq_d((((double)va - m) * r) * gg + bb);
    double qb = fq_d((((double)vb - m) * r) * gg + bb);
    qa = fmax(qa, 0.0); qb = fmax(qb, 0.0);
    ushort2 pk; pk.x = bfbits(qa); pk.y = bfbits(qb);
    *(ushort2*)&p1[((size_t)b * 6 + c) * 196 + ph * 14 + 2 * pp] = pk;
}

// ---------------- conv2 as implicit GEMM on v_mfma_f64_16x16x4_f64 --------
// [B,6,14,14] -> [B,100,16] (position-major output). 8 images/block,
// 320 thr = 5 waves, grid 1024 (r13 LOW-TRAFFIC geometry). M = 800
// positions (50 exact 16-tiles, 10/wave), N = 16 co, K = 152 (150+2 pad).
// k-slot remap: MFMA m (0..37) pairs lane-group c with k = m + 38c
// (A/B same grouping -> exact sum invariant, r13-verified). Offsets pure
// arithmetic (magic-div), B address linear in m. ILP-2 chains/tile.
// Weights staged coalesced from qw2t (r16). LDS-bounce 512B stores (r17).
// D-side (reg,lane)->(row,col) mapping PROBED at runtime (r13-verified).
__global__ __launch_bounds__(320) void kconv2(const __hip_bfloat16* __restrict__ p1,
        const float* __restrict__ qw2t, __hip_bfloat16* __restrict__ c2,
        double* __restrict__ st2) {
    __shared__ float sxf[9408];        // 8 x [6][14][14] f32 (exact grid vals)
    __shared__ float swf[2432];        // [152][16] f32 weights, k-major (exact)
    __shared__ unsigned short sep[5][256];  // per-wave 16x16 bf16 out tile
    __shared__ double sred[16][2];
    int t = threadIdx.x;
    int b0 = blockIdx.x * 8;
    // stage x: 9408 bf16 -> f32, vectorized ushort4 (8B, coalesced)
    const ushort4* srcp = (const ushort4*)(p1 + (size_t)b0 * 1176);
    for (int i = t; i < 2352; i += 320) {
        ushort4 u = srcp[i];
        float* d = &sxf[4 * i];
        d[0] = bfval(u.x);
        d[1] = bfval(u.y);
        d[2] = bfval(u.z);
        d[3] = bfval(u.w);
    }
    // stage weights: pure coalesced copy (608 x float4, L2-resident)
    {
        const float4* wsrc = (const float4*)qw2t;
        float4* wdst = (float4*)swf;
        for (int i = t; i < 608; i += 320) wdst[i] = wsrc[i];
    }
    if (t < 32) ((double*)sred)[t] = 0.0;
    __syncthreads();

    int l = t & 63, w = t >> 6;        // lane, wave
    int c = l >> 4, r16 = l & 15;      // k-group / {A-row,B-col} staging index

    // ---- layout probes (exact small-int arithmetic, 2 MFMAs) ----
    d4 pz = {0.0, 0.0, 0.0, 0.0};
    d4 prow = __builtin_amdgcn_mfma_f64_16x16x4f64((double)r16, 0.25, pz, 0, 0, 0);
    d4 pcol = __builtin_amdgcn_mfma_f64_16x16x4f64(1.0, 0.25 * (double)r16, pz, 0, 0, 0);
    int rowidx[4], colidx[4];
    #pragma unroll
    for (int j = 0; j < 4; ++j) { rowidx[j] = (int)prow[j]; colidx[j] = (int)pcol[j]; }

    int kbase = 38 * c;                // lane's contiguous k-range start
    unsigned short* myep = sep[w];
    double ls = 0.0, ls2 = 0.0;        // per-lane stats (col fixed per lane)
    int co0 = colidx[0];
    for (int tile = w; tile < 50; tile += 5) {
        int pos = tile * 16 + r16;     // A-row (staging) for this lane
        int abase = (pos / 100) * 1176 + ((pos % 100) / 10) * 14 + (pos % 10);
        d4 a0 = {0.0, 0.0, 0.0, 0.0}, a1 = {0.0, 0.0, 0.0, 0.0};
        #pragma unroll
        for (int s = 0; s < 19; ++s) {
            int k0 = kbase + s;        // chain 0: m = s
            int k1 = kbase + s + 19;   // chain 1: m = s + 19
            int i0 = abase + patch_off(k0);
            int i1 = abase + patch_off(k1);
            // pad slots (k>=150, only c=3) map OOB; clamp to any in-range
            // address — their B weight is exactly 0, so finite*0 = 0.
            if (i0 > 9407) i0 = 0;
            if (i1 > 9407) i1 = 0;
            double x0 = (double)sxf[i0];
            double x1 = (double)sxf[i1];
            double w0 = (double)swf[k0 * 16 + r16];
            double w1 = (double)swf[k1 * 16 + r16];
            a0 = __builtin_amdgcn_mfma_f64_16x16x4f64(x0, w0, a0, 0, 0, 0);
            a1 = __builtin_amdgcn_mfma_f64_16x16x4f64(x1, w1, a1, 0, 0, 0);
        }
        // epilogue: fq + stats; assemble tile in LDS (probed mapping), then
        // ONE coalesced 512B wave store (c2 tile region is contiguous).
        #pragma unroll
        for (int j = 0; j < 4; ++j) {
            double q = fq_d(a0[j] + a1[j]);
            myep[rowidx[j] * 16 + colidx[j]] = bfbits(q);
            ls += q; ls2 += q * q;
        }
        ushort4 v = *(const ushort4*)&myep[l * 4];   // wave-internal, in-order
        *(ushort4*)((unsigned short*)c2 + ((size_t)b0 * 100 + tile * 16) * 16 + l * 4) = v;
    }
    atomicAdd(&sred[co0][0], ls);
    atomicAdd(&sred[co0][1], ls2);
    __syncthreads();
    if (t < 32) atomicAdd(&st2[t * 32 + (blockIdx.x & 31)], ((double*)sred)[t]);
}

// ---------------- fc1: fused bn2-finalize + bn2/fq/relu/pool staging -------
// BT=8 (1024 blocks): c2 [B,100,16] position-major. Pool reads global
// directly with c-fastest map: 16 consecutive channels per 16-thread
// cluster -> 32B-contiguous loads. LDS 25.9KB -> 6 blocks/CU.
__global__ __launch_bounds__(256) void kfc1(const __hip_bfloat16* __restrict__ c2,
        const double* __restrict__ st2, const float* __restrict__ g2,
        const float* __restrict__ be2, const float* __restrict__ Wt,
        const float* __restrict__ qb, __hip_bfloat16* __restrict__ outb) {
    constexpr int IN = 400, OUT = 120, OUTP = 128, ROWS = 4, BT = 8;
    __shared__ double sx[BT][IN];
    __shared__ double sbn[16][4];
    int t = threadIdx.x;
    int b0 = blockIdx.x * BT;
    if (t < 16) {                       // inline bn2 finalize from stat bins
        double s = 0.0, s2 = 0.0;
        for (int b = 0; b < 32; ++b) { s += st2[t * 64 + b]; s2 += st2[t * 64 + 32 + b]; }
        double m = s / (819200.0);      // 8192*100
        double v = s2 / (819200.0) - m * m;
        sbn[t][0] = m; sbn[t][1] = 1.0 / sqrt(v + 1e-5);
        sbn[t][2] = (double)g2[t]; sbn[t][3] = (double)be2[t];
    }
    __syncthreads();
    for (int i = t; i < BT * IN; i += 256) {
        int cc = i & 15;                // channel fastest (coalesced)
        int rem = (i >> 4) % 25;        // pooled position
        int r = i / 400;                // image row within tile
        int ph = rem / 5, pw = rem % 5;
        const __hip_bfloat16* src = c2 + ((size_t)(b0 + r) * 100 + 20 * ph + 2 * pw) * 16 + cc;
        double m = sbn[cc][0], rr = sbn[cc][1], gg = sbn[cc][2], bb = sbn[cc][3];
        float f0 = __bfloat162float(src[0]),   f1 = __bfloat162float(src[16]);
        float f2 = __bfloat162float(src[160]), f3 = __bfloat162float(src[176]);
        bool useMax = (rr * gg) >= 0.0;
        float v = useMax ? fmaxf(fmaxf(f0, f1), fmaxf(f2, f3))
                         : fminf(fminf(f0, f1), fminf(f2, f3));
        double q = fq_d((((double)v - m) * rr) * gg + bb);
        sx[r][cc * 25 + rem] = fmax(q, 0.0);
    }
    __syncthreads();
    int o = t % OUTP;
    int g = t / OUTP;
    double acc[ROWS];
    double bias = (o < OUT) ? (double)qb[o] : 0.0;
    #pragma unroll
    for (int r = 0; r < ROWS; ++r) acc[r] = bias;
    #pragma unroll 4
    for (int k = 0; k < IN; ++k) {
        double w = (double)Wt[k * OUTP + o];   // coalesced, L2-resident
        #pragma unroll
        for (int r = 0; r < ROWS; ++r)
            acc[r] = fma(sx[g * ROWS + r][k], w, acc[r]);
    }
    if (o < OUT) {
        #pragma unroll
        for (int r = 0; r < ROWS; ++r) {
            double q = fq_d(acc[r]);
            if (q < 0.0) q = 0.0;
            outb[(size_t)(b0 + g * ROWS + r) * OUT + o] = __float2bfloat16((float)q);
        }
    }
}

// ---------------- fused fc2+fc3: a1 [B,120] -> out [B,10] ----------------
__global__ __launch_bounds__(256) void kfc23(const __hip_bfloat16* __restrict__ a1,
        const float* __restrict__ Wt2, const float* __restrict__ qfb2,
        const float* __restrict__ Wt3, const float* __restrict__ qfb3,
        float* __restrict__ out) {
    __shared__ double sx1[16][120];
    __shared__ double s2[16][84];
    int t = threadIdx.x;
    int b0 = blockIdx.x * 16;
    for (int i = t; i < 16 * 120; i += 256) {
        int r = i / 120, k = i % 120;
        sx1[r][k] = (double)__bfloat162float(a1[(size_t)(b0 + r) * 120 + k]);
    }
    __syncthreads();
    {   // fc2: 2 groups x 8 rows x 128 output lanes
        int o = t % 128, g = t / 128;
        double acc[8];
        double bias = (o < 84) ? (double)qfb2[o] : 0.0;
        #pragma unroll
        for (int r = 0; r < 8; ++r) acc[r] = bias;
        #pragma unroll 4
        for (int k = 0; k < 120; ++k) {
            double w = (double)Wt2[k * 128 + o];
            #pragma unroll
            for (int r = 0; r < 8; ++r)
                acc[r] = fma(sx1[g * 8 + r][k], w, acc[r]);
        }
        if (o < 84) {
            #pragma unroll
            for (int r = 0; r < 8; ++r) {
                double q = fq_d(acc[r]);
                s2[g * 8 + r][o] = fmax(q, 0.0);
            }
        }
    }
    __syncthreads();
    {   // fc3: 16 rows x 16 output lanes (10 used)
        int o = t % 16, g = t / 16;
        double acc = (o < 10) ? (double)qfb3[o] : 0.0;
        #pragma unroll 4
        for (int k = 0; k < 84; ++k)
            acc = fma(s2[g][k], (double)Wt3[k * 16 + o], acc);
        if (o < 10)
            out[(size_t)(b0 + g) * 10 + o] = (float)fq_d(acc);
    }
}

// ---------------------------------------------------------------------------
extern "C" void kernel_launch(void* const* d_in, const int* in_sizes, int n_in,
                              void* d_out, int out_size, void* d_ws, size_t ws_size,
                              hipStream_t stream) {
    const float* x   = (const float*)d_in[0];
    const float* w1  = (const float*)d_in[1];
    const float* g1  = (const float*)d_in[2];
    const float* be1 = (const float*)d_in[3];
    const float* w2  = (const float*)d_in[4];
    const float* g2  = (const float*)d_in[5];
    const float* be2 = (const float*)d_in[6];
    const float* fw1 = (const float*)d_in[7];
    const float* fb1 = (const float*)d_in[8];
    const float* fw2 = (const float*)d_in[9];
    const float* fb2 = (const float*)d_in[10];
    const float* fw3 = (const float*)d_in[11];
    const float* fb3 = (const float*)d_in[12];

    char* ws = (char*)d_ws;
    double* stats1 = (double*)(ws + 0);      // [6][2][32] dbl
    double* stats2 = (double*)(ws + 3072);   // [16][2][32] dbl (ends 11264)
    double* mr1    = (double*)(ws + 11264);  // 12 dbl
    float* qw1  = (float*)(ws + 12288);
    float* qw2t = (float*)(ws + 13312);      // [152][16] f32, ends 23040
    float* qfb1 = (float*)(ws + 23040);
    float* qfb2 = (float*)(ws + 23552);
    float* qfb3 = (float*)(ws + 24064);
    float* Wt1  = (float*)(ws + 24576);      // 400*128
    float* Wt2  = (float*)(ws + 229376);     // 120*128
    float* Wt3  = (float*)(ws + 290816);     // 84*16
    __hip_bfloat16* c1 = (__hip_bfloat16*)(ws + 303104);      // [B,6,28,28] 77.1 MB
    __hip_bfloat16* p1 = (__hip_bfloat16*)(ws + 77373440);    // [B,6,14,14] 19.3 MB
    __hip_bfloat16* c2 = (__hip_bfloat16*)(ws + 303104);      // [B,100,16] (c1 dead)
    __hip_bfloat16* a1 = (__hip_bfloat16*)(ws + 303104 + 26214400); // [B,120]

    hipMemsetAsync(ws, 0, 11264, stream);

    kprep<<<(PREP_TOTAL + 255) / 256, 256, 0, stream>>>(
        w1, w2, fb1, fb2, fb3, fw1, fw2, fw3,
        qw1, qw2t, qfb1, qfb2, qfb3, Wt1, Wt2, Wt3);

    // conv1 + fq + stats -> c1   (3 images/block, 2x7 tiles)
    kconv1<<<(BATCH + 2) / 3, 256, 0, stream>>>(x, qw1, c1, BATCH, stats1);
    kfinal<<<1, 32, 0, stream>>>(stats1, mr1, 6, (double)BATCH * 784.0);
    // bn1 + fq + relu + pool -> p1
    kpool1<<<BATCH * 6 * 14 * 7 / 256, 256, 0, stream>>>(c1, mr1, g1, be1, p1);
    // conv2 via f64 MFMA implicit GEMM (r13 geometry x r17 code) -> c2
    kconv2<<<BATCH / 8, 320, 0, stream>>>(p1, qw2t, c2, stats2);
    // fc1 (inline bn2 finalize + fused pool staging, +relu) -> a1 [B,120]
    kfc1<<<BATCH / 8, 256, 0, stream>>>(c2, stats2, g2, be2, Wt1, qfb1, a1);
    // fused fc2+fc3 -> d_out [B,10] float
    kfc23<<<BATCH / 16, 256, 0, stream>>>(a1, Wt2, qfb2, Wt3, qfb3, (float*)d_out);
}

// Round 8
// 395.373 us; speedup vs baseline: 1.3063x; 1.1339x over previous
//
#include <hip/hip_runtime.h>
#include <hip/hip_bf16.h>

// ---------------------------------------------------------------------------
// QLenet forward, exact-math strategy:
//   All fq() outputs are e5m2 grid values (<=3 significant bits). Products of
//   two grid values have <=6-bit mantissas; dot sums (<=400 terms, bounded
//   exponent span) are EXACT in f64 -> order-independent -> matches float64
//   numpy reference. Intermediates stored as bf16 (exact for grid values);
//   LDS tiles hold f32 (also exact), accumulation stays f64.
// Round 18 -> 19:
//   * r18 confirmed the traffic law (grid 1024 -> FETCH 9.5MB) but MfmaUtil
//     stayed 29.5%: accumulator ILP never was the constraint (r13 ILP-1 =
//     r14 ILP-4 = r18 ILP-2 ~ 30%). Waves wait ~70% on the operand path
//     (addr->ds_read->cvt); the scaling lever is resident WAVES (r15: 44%).
//     Also r18's k=s+38c remap made weight reads a 4-way bank conflict
//     (group stride 608 words = 0 mod 32 banks; conflicts 850K->4.66M).
//   * r19: 512-thr/8-wave blocks, SAME grid 1024 (waves share block LDS ->
//     global traffic unchanged, stays in low-traffic regime); k-mapping
//     reverted to k=4m+c (2-way benign, r13-verified); ILP-2 kept.
// ---------------------------------------------------------------------------

#define BATCH 8192

typedef double d4 __attribute__((ext_vector_type(4)));

// fq on f64: round to FP(e5m2) nearest-even, subnormal granule 2^-16,
// clip +-57344. Integer RNE on the mantissa; carry propagates into exponent.
__device__ __forceinline__ double fq_d(double x) {
    long long b = __double_as_longlong(x);
    long long ab = b & 0x7fffffffffffffffLL;
    if (ab == 0) return x;                       // +-0 preserved
    double q;
    if (ab >= 0x3F10000000000000LL) {            // |x| >= 2^-14
        long long r = b + 0x0001FFFFFFFFFFFFLL + ((b >> 50) & 1LL);
        r &= 0xFFFC000000000000LL;
        q = __longlong_as_double(r);
        q = fmin(fmax(q, -57344.0), 57344.0);
    } else {                                     // subnormal grid: 2^-16
        q = rint(x * 65536.0) * 1.52587890625e-05;
    }
    return q;
}

// fq on f32 input values (exact f32 -> same e5m2 result as the f64 path).
__device__ __forceinline__ float fq_f(float x) {
    int b = __float_as_int(x);
    int ab = b & 0x7fffffff;
    if (ab == 0) return x;
    float q;
    if (ab >= 0x38800000) {                      // |x| >= 2^-14
        int r = b + 0x000FFFFF + ((b >> 21) & 1);
        r &= 0xFFE00000;                         // sign+exp+2 mantissa bits
        q = __int_as_float(r);
        q = fminf(fmaxf(q, -57344.0f), 57344.0f);
    } else {
        q = rintf(x * 65536.0f) * 1.52587890625e-05f;
    }
    return q;
}

__device__ __forceinline__ unsigned short bfbits(double q) {
    __hip_bfloat16 h = __float2bfloat16((float)q);   // exact for grid values
    return *(unsigned short*)&h;
}

__device__ __forceinline__ float bfval(unsigned short u) {
    return __bfloat162float(*(__hip_bfloat16*)&u);
}

// patch offset for flat k in [0,152): k = ci*25 + u*5 + v -> ci*196+u*14+v.
// Exact magic-div (verified for all k<=151); pad k>=150 handled by caller.
__device__ __forceinline__ int patch_off(int k) {
    int ci = (k * 1311) >> 15;      // k/25, exact for k<=151
    int rem = k - 25 * ci;
    int u = (rem * 13) >> 6;        // rem/5, exact for rem<25
    int v = rem - 5 * u;
    return ci * 196 + u * 14 + v;
}

// ---------------- merged prep (all f32-path fq) ----------------
// qw2t: conv2 weights pre-transposed to [152][16] f32 (k-major, zero-padded)
// so kconv2's LDS staging is a pure coalesced copy.
__global__ void kprep(const float* __restrict__ w1, const float* __restrict__ w2,
                      const float* __restrict__ fb1, const float* __restrict__ fb2,
                      const float* __restrict__ fb3, const float* __restrict__ fw1,
                      const float* __restrict__ fw2, const float* __restrict__ fw3,
                      float* __restrict__ qw1, float* __restrict__ qw2t,
                      float* __restrict__ qfb1, float* __restrict__ qfb2,
                      float* __restrict__ qfb3, float* __restrict__ Wt1,
                      float* __restrict__ Wt2, float* __restrict__ Wt3) {
    int i = blockIdx.x * 256 + threadIdx.x;
    if (i < 150) { qw1[i] = fq_f(w1[i]); return; }
    i -= 150;
    if (i < 2432) { int k = i >> 4, co = i & 15;
        qw2t[i] = (k < 150) ? fq_f(w2[co * 150 + k]) : 0.0f; return; }
    i -= 2432;
    if (i < 120) { qfb1[i] = fq_f(fb1[i]); return; }
    i -= 120;
    if (i < 84) { qfb2[i] = fq_f(fb2[i]); return; }
    i -= 84;
    if (i < 10) { qfb3[i] = fq_f(fb3[i]); return; }
    i -= 10;
    if (i < 51200) { int k = i / 128, o = i % 128;
        Wt1[i] = (o < 120) ? fq_f(fw1[o * 400 + k]) : 0.0f; return; }
    i -= 51200;
    if (i < 15360) { int k = i / 128, o = i % 128;
        Wt2[i] = (o < 84) ? fq_f(fw2[o * 120 + k]) : 0.0f; return; }
    i -= 15360;
    if (i < 1344) { int k = i / 16, o = i % 16;
        Wt3[i] = (o < 10) ? fq_f(fw3[o * 84 + k]) : 0.0f; return; }
}
#define PREP_TOTAL (150 + 2432 + 120 + 84 + 10 + 51200 + 15360 + 1344)

// ---------------- conv1 + fq + fused BN stats (r9 version) ----------------
// [B,1,32,32] -> [B,6,28,28]. 3 images/block; task = 2x7 output tile with
// rotated-w row reuse. x tile f32 (fq_f staging), stride 33.
__global__ __launch_bounds__(256) void kconv1(const float* __restrict__ x,
        const float* __restrict__ qw, __hip_bfloat16* __restrict__ c1,
        int nimg_total, double* __restrict__ st1) {
    __shared__ float sxf[3 * 1056];   // 3 x (32 rows x 33) f32
    __shared__ double swd[152];
    __shared__ double sred[6][2];
    int t = threadIdx.x;
    int b0 = blockIdx.x * 3;
    int nimg = nimg_total - b0; if (nimg > 3) nimg = 3;
    for (int i = t; i < nimg * 1024; i += 256) {
        int img = i >> 10, idx = i & 1023;
        sxf[img * 1056 + (idx >> 5) * 33 + (idx & 31)] =
            fq_f(x[(size_t)(b0 + img) * 1024 + idx]);
    }
    if (t < 150) swd[t] = (double)qw[t];
    if (t >= 192 && t < 204) ((double*)sred)[t - 192] = 0.0;
    __syncthreads();
    int ntask = nimg * 336;           // 6 co x 14 rowpairs x 4 colchunks
    for (int task = t; task < ntask; task += 256) {
        int img = task / 336; int rr = task % 336;
        int co = rr / 56; int rem = rr % 56;
        int i0 = (rem >> 2) * 2;      // 0,2,...,26
        int j0 = (rem & 3) * 7;       // 0,7,14,21
        const double* wp = &swd[co * 25];
        double a0[7], a1[7];
        #pragma unroll
        for (int j = 0; j < 7; ++j) { a0[j] = 0.0; a1[j] = 0.0; }
        double wr[5], wq[5];
        #pragma unroll
        for (int u = 0; u < 6; ++u) {
            const float* xr = &sxf[img * 1056 + (i0 + u) * 33 + j0];
            double xv[11];
            #pragma unroll
            for (int k = 0; k < 11; ++k) xv[k] = (double)xr[k];
            if (u < 5) {
                #pragma unroll
                for (int tt = 0; tt < 5; ++tt) wr[tt] = wp[u * 5 + tt];
                #pragma unroll
                for (int j = 0; j < 7; ++j)
                    a0[j] = fma(xv[j], wr[0], fma(xv[j+1], wr[1], fma(xv[j+2], wr[2],
                            fma(xv[j+3], wr[3], fma(xv[j+4], wr[4], a0[j])))));
            }
            if (u >= 1) {
                #pragma unroll
                for (int j = 0; j < 7; ++j)
                    a1[j] = fma(xv[j], wq[0], fma(xv[j+1], wq[1], fma(xv[j+2], wq[2],
                            fma(xv[j+3], wq[3], fma(xv[j+4], wq[4], a1[j])))));
            }
            #pragma unroll
            for (int tt = 0; tt < 5; ++tt) wq[tt] = wr[tt];   // SSA rotate
        }
        size_t base = ((size_t)(b0 + img) * 6 + co) * 784 + (size_t)i0 * 28 + j0;
        double s = 0.0, s2 = 0.0;
        #pragma unroll
        for (int j = 0; j < 7; ++j) {
            double q0 = fq_d(a0[j]), q1 = fq_d(a1[j]);
            ((unsigned short*)c1)[base + j]      = bfbits(q0);
            ((unsigned short*)c1)[base + 28 + j] = bfbits(q1);
            s += q0 + q1; s2 += q0 * q0 + q1 * q1;
        }
        atomicAdd(&sred[co][0], s);
        atomicAdd(&sred[co][1], s2);
    }
    __syncthreads();
    if (t < 12) atomicAdd(&st1[t * 32 + (blockIdx.x & 31)], ((double*)sred)[t]);
}

// ---------------- finalize BN1 from 32-binned stats ----------------
__global__ void kfinal(const double* __restrict__ st, double* __restrict__ mr,
                       int C, double N) {
    int c = threadIdx.x;
    if (c < C) {
        double s = 0.0, s2 = 0.0;
        for (int b = 0; b < 32; ++b) { s += st[c * 64 + b]; s2 += st[c * 64 + 32 + b]; }
        double m = s / N;
        double v = s2 / N - m * m;
        mr[2 * c] = m;
        mr[2 * c + 1] = 1.0 / sqrt(v + 1e-5);
    }
}

// ---------------- bn1 + fq + relu + 2x2 pool (monotone single-fq) ----------
__global__ __launch_bounds__(256) void kpool1(const __hip_bfloat16* __restrict__ c1,
        const double* __restrict__ mr1, const float* __restrict__ g1,
        const float* __restrict__ be1, __hip_bfloat16* __restrict__ p1) {
    int idx = blockIdx.x * 256 + threadIdx.x;   // pair-task: B*6*14*7
    int pp = idx % 7;  int t1 = idx / 7;
    int ph = t1 % 14;  int t2 = t1 / 14;
    int c  = t2 % 6;   int b  = t2 / 6;
    double m = mr1[2 * c], r = mr1[2 * c + 1];
    double gg = (double)g1[c], bb = (double)be1[c];
    bool useMax = (r * gg) >= 0.0;              // selection only
    const __hip_bfloat16* src = c1 + (((size_t)b * 6 + c) * 28 + 2 * ph) * 28 + 4 * pp;
    ushort4 u0 = *(const ushort4*)src;
    ushort4 u1 = *(const ushort4*)(src + 28);
    float f0 = bfval(u0.x), f1 = bfval(u0.y);
    float f2 = bfval(u0.z), f3 = bfval(u0.w);
    float f4 = bfval(u1.x), f5 = bfval(u1.y);
    float f6 = bfval(u1.z), f7 = bfval(u1.w);
    float va = useMax ? fmaxf(fmaxf(f0, f1), fmaxf(f4, f5))
                      : fminf(fminf(f0, f1), fminf(f4, f5));
    float vb = useMax ? fmaxf(fmaxf(f2, f3), fmaxf(f6, f7))
                      : fminf(fminf(f2, f3), fminf(f6, f7));
    double qa = fq_d((((double)va - m) * r) * gg + bb);
    double qb = fq_d((((double)vb - m) * r) * gg + bb);
    qa = fmax(qa, 0.0); qb = fmax(qb, 0.0);
    ushort2 pk; pk.x = bfbits(qa); pk.y = bfbits(qb);
    *(ushort2*)&p1[((size_t)b * 6 + c) * 196 + ph * 14 + 2 * pp] = pk;
}

// ---------------- conv2 as implicit GEMM on v_mfma_f64_16x16x4_f64 --------
// [B,6,14,14] -> [B,100,16] (position-major output). 8 images/block,
// 512 thr = 8 waves, grid 1024 (low-traffic geometry; waves share the
// block's LDS tiles so global traffic is unchanged vs r18). M = 800
// positions (50 exact 16-tiles, 6-7/wave), N = 16 co, K = 152 (150+2 pad).
// k-mapping k = 4m + c (2-way bank-benign, r13-verified; r18's k=s+38c was
// a 4-way weight-read conflict). Offsets pure arithmetic (magic-div).
// ILP-2 chains/tile. Weights staged coalesced from qw2t (r16). LDS-bounce
// 512B stores (r17). D-side mapping PROBED at runtime (r13-verified).
__global__ __launch_bounds__(512) void kconv2(const __hip_bfloat16* __restrict__ p1,
        const float* __restrict__ qw2t, __hip_bfloat16* __restrict__ c2,
        double* __restrict__ st2) {
    __shared__ float sxf[9408];        // 8 x [6][14][14] f32 (exact grid vals)
    __shared__ float swf[2432];        // [152][16] f32 weights, k-major (exact)
    __shared__ unsigned short sep[8][256];  // per-wave 16x16 bf16 out tile
    __shared__ double sred[16][2];
    int t = threadIdx.x;
    int b0 = blockIdx.x * 8;
    // stage x: 9408 bf16 -> f32, vectorized ushort4 (8B, coalesced)
    const ushort4* srcp = (const ushort4*)(p1 + (size_t)b0 * 1176);
    for (int i = t; i < 2352; i += 512) {
        ushort4 u = srcp[i];
        float* d = &sxf[4 * i];
        d[0] = bfval(u.x);
        d[1] = bfval(u.y);
        d[2] = bfval(u.z);
        d[3] = bfval(u.w);
    }
    // stage weights: pure coalesced copy (608 x float4, L2-resident)
    {
        const float4* wsrc = (const float4*)qw2t;
        float4* wdst = (float4*)swf;
        for (int i = t; i < 608; i += 512) wdst[i] = wsrc[i];
    }
    if (t < 32) ((double*)sred)[t] = 0.0;
    __syncthreads();

    int l = t & 63, w = t >> 6;        // lane, wave (0..7)
    int c = l >> 4, r16 = l & 15;      // k-group / {A-row,B-col} staging index

    // ---- layout probes (exact small-int arithmetic, 2 MFMAs) ----
    d4 pz = {0.0, 0.0, 0.0, 0.0};
    d4 prow = __builtin_amdgcn_mfma_f64_16x16x4f64((double)r16, 0.25, pz, 0, 0, 0);
    d4 pcol = __builtin_amdgcn_mfma_f64_16x16x4f64(1.0, 0.25 * (double)r16, pz, 0, 0, 0);
    int rowidx[4], colidx[4];
    #pragma unroll
    for (int j = 0; j < 4; ++j) { rowidx[j] = (int)prow[j]; colidx[j] = (int)pcol[j]; }

    unsigned short* myep = sep[w];
    double ls = 0.0, ls2 = 0.0;        // per-lane stats (col fixed per lane)
    int co0 = colidx[0];
    for (int tile = w; tile < 50; tile += 8) {
        int pos = tile * 16 + r16;     // A-row (staging) for this lane
        int abase = (pos / 100) * 1176 + ((pos % 100) / 10) * 14 + (pos % 10);
        d4 a0 = {0.0, 0.0, 0.0, 0.0}, a1 = {0.0, 0.0, 0.0, 0.0};
        #pragma unroll
        for (int s = 0; s < 19; ++s) {
            int k0 = 4 * s + c;              // chain 0: m = s
            int k1 = 4 * (s + 19) + c;       // chain 1: m = s + 19
            int i0 = abase + patch_off(k0);
            int i1 = abase + patch_off(k1);
            // pad slots (k>=150: m=37, c>=2) map OOB; clamp in-range —
            // their B weight is exactly 0, so finite*0 = 0.
            if (i0 > 9407) i0 = 0;
            if (i1 > 9407) i1 = 0;
            double x0 = (double)sxf[i0];
            double x1 = (double)sxf[i1];
            double w0 = (double)swf[k0 * 16 + r16];
            double w1 = (double)swf[k1 * 16 + r16];
            a0 = __builtin_amdgcn_mfma_f64_16x16x4f64(x0, w0, a0, 0, 0, 0);
            a1 = __builtin_amdgcn_mfma_f64_16x16x4f64(x1, w1, a1, 0, 0, 0);
        }
        // epilogue: fq + stats; assemble tile in LDS (probed mapping), then
        // ONE coalesced 512B wave store (c2 tile region is contiguous).
        #pragma unroll
        for (int j = 0; j < 4; ++j) {
            double q = fq_d(a0[j] + a1[j]);
            myep[rowidx[j] * 16 + colidx[j]] = bfbits(q);
            ls += q; ls2 += q * q;
        }
        ushort4 v = *(const ushort4*)&myep[l * 4];   // wave-internal, in-order
        *(ushort4*)((unsigned short*)c2 + ((size_t)b0 * 100 + tile * 16) * 16 + l * 4) = v;
    }
    atomicAdd(&sred[co0][0], ls);
    atomicAdd(&sred[co0][1], ls2);
    __syncthreads();
    if (t < 32) atomicAdd(&st2[t * 32 + (blockIdx.x & 31)], ((double*)sred)[t]);
}

// ---------------- fc1: fused bn2-finalize + bn2/fq/relu/pool staging -------
// BT=8 (1024 blocks): c2 [B,100,16] position-major. Pool reads global
// directly with c-fastest map: 16 consecutive channels per 16-thread
// cluster -> 32B-contiguous loads. LDS 25.9KB -> 6 blocks/CU.
__global__ __launch_bounds__(256) void kfc1(const __hip_bfloat16* __restrict__ c2,
        const double* __restrict__ st2, const float* __restrict__ g2,
        const float* __restrict__ be2, const float* __restrict__ Wt,
        const float* __restrict__ qb, __hip_bfloat16* __restrict__ outb) {
    constexpr int IN = 400, OUT = 120, OUTP = 128, ROWS = 4, BT = 8;
    __shared__ double sx[BT][IN];
    __shared__ double sbn[16][4];
    int t = threadIdx.x;
    int b0 = blockIdx.x * BT;
    if (t < 16) {                       // inline bn2 finalize from stat bins
        double s = 0.0, s2 = 0.0;
        for (int b = 0; b < 32; ++b) { s += st2[t * 64 + b]; s2 += st2[t * 64 + 32 + b]; }
        double m = s / (819200.0);      // 8192*100
        double v = s2 / (819200.0) - m * m;
        sbn[t][0] = m; sbn[t][1] = 1.0 / sqrt(v + 1e-5);
        sbn[t][2] = (double)g2[t]; sbn[t][3] = (double)be2[t];
    }
    __syncthreads();
    for (int i = t; i < BT * IN; i += 256) {
        int cc = i & 15;                // channel fastest (coalesced)
        int rem = (i >> 4) % 25;        // pooled position
        int r = i / 400;                // image row within tile
        int ph = rem / 5, pw = rem % 5;
        const __hip_bfloat16* src = c2 + ((size_t)(b0 + r) * 100 + 20 * ph + 2 * pw) * 16 + cc;
        double m = sbn[cc][0], rr = sbn[cc][1], gg = sbn[cc][2], bb = sbn[cc][3];
        float f0 = __bfloat162float(src[0]),   f1 = __bfloat162float(src[16]);
        float f2 = __bfloat162float(src[160]), f3 = __bfloat162float(src[176]);
        bool useMax = (rr * gg) >= 0.0;
        float v = useMax ? fmaxf(fmaxf(f0, f1), fmaxf(f2, f3))
                         : fminf(fminf(f0, f1), fminf(f2, f3));
        double q = fq_d((((double)v - m) * rr) * gg + bb);
        sx[r][cc * 25 + rem] = fmax(q, 0.0);
    }
    __syncthreads();
    int o = t % OUTP;
    int g = t / OUTP;
    double acc[ROWS];
    double bias = (o < OUT) ? (double)qb[o] : 0.0;
    #pragma unroll
    for (int r = 0; r < ROWS; ++r) acc[r] = bias;
    #pragma unroll 4
    for (int k = 0; k < IN; ++k) {
        double w = (double)Wt[k * OUTP + o];   // coalesced, L2-resident
        #pragma unroll
        for (int r = 0; r < ROWS; ++r)
            acc[r] = fma(sx[g * ROWS + r][k], w, acc[r]);
    }
    if (o < OUT) {
        #pragma unroll
        for (int r = 0; r < ROWS; ++r) {
            double q = fq_d(acc[r]);
            if (q < 0.0) q = 0.0;
            outb[(size_t)(b0 + g * ROWS + r) * OUT + o] = __float2bfloat16((float)q);
        }
    }
}

// ---------------- fused fc2+fc3: a1 [B,120] -> out [B,10] ----------------
__global__ __launch_bounds__(256) void kfc23(const __hip_bfloat16* __restrict__ a1,
        const float* __restrict__ Wt2, const float* __restrict__ qfb2,
        const float* __restrict__ Wt3, const float* __restrict__ qfb3,
        float* __restrict__ out) {
    __shared__ double sx1[16][120];
    __shared__ double s2[16][84];
    int t = threadIdx.x;
    int b0 = blockIdx.x * 16;
    for (int i = t; i < 16 * 120; i += 256) {
        int r = i / 120, k = i % 120;
        sx1[r][k] = (double)__bfloat162float(a1[(size_t)(b0 + r) * 120 + k]);
    }
    __syncthreads();
    {   // fc2: 2 groups x 8 rows x 128 output lanes
        int o = t % 128, g = t / 128;
        double acc[8];
        double bias = (o < 84) ? (double)qfb2[o] : 0.0;
        #pragma unroll
        for (int r = 0; r < 8; ++r) acc[r] = bias;
        #pragma unroll 4
        for (int k = 0; k < 120; ++k) {
            double w = (double)Wt2[k * 128 + o];
            #pragma unroll
            for (int r = 0; r < 8; ++r)
                acc[r] = fma(sx1[g * 8 + r][k], w, acc[r]);
        }
        if (o < 84) {
            #pragma unroll
            for (int r = 0; r < 8; ++r) {
                double q = fq_d(acc[r]);
                s2[g * 8 + r][o] = fmax(q, 0.0);
            }
        }
    }
    __syncthreads();
    {   // fc3: 16 rows x 16 output lanes (10 used)
        int o = t % 16, g = t / 16;
        double acc = (o < 10) ? (double)qfb3[o] : 0.0;
        #pragma unroll 4
        for (int k = 0; k < 84; ++k)
            acc = fma(s2[g][k], (double)Wt3[k * 16 + o], acc);
        if (o < 10)
            out[(size_t)(b0 + g) * 10 + o] = (float)fq_d(acc);
    }
}

// ---------------------------------------------------------------------------
extern "C" void kernel_launch(void* const* d_in, const int* in_sizes, int n_in,
                              void* d_out, int out_size, void* d_ws, size_t ws_size,
                              hipStream_t stream) {
    const float* x   = (const float*)d_in[0];
    const float* w1  = (const float*)d_in[1];
    const float* g1  = (const float*)d_in[2];
    const float* be1 = (const float*)d_in[3];
    const float* w2  = (const float*)d_in[4];
    const float* g2  = (const float*)d_in[5];
    const float* be2 = (const float*)d_in[6];
    const float* fw1 = (const float*)d_in[7];
    const float* fb1 = (const float*)d_in[8];
    const float* fw2 = (const float*)d_in[9];
    const float* fb2 = (const float*)d_in[10];
    const float* fw3 = (const float*)d_in[11];
    const float* fb3 = (const float*)d_in[12];

    char* ws = (char*)d_ws;
    double* stats1 = (double*)(ws + 0);      // [6][2][32] dbl
    double* stats2 = (double*)(ws + 3072);   // [16][2][32] dbl (ends 11264)
    double* mr1    = (double*)(ws + 11264);  // 12 dbl
    float* qw1  = (float*)(ws + 12288);
    float* qw2t = (float*)(ws + 13312);      // [152][16] f32, ends 23040
    float* qfb1 = (float*)(ws + 23040);
    float* qfb2 = (float*)(ws + 23552);
    float* qfb3 = (float*)(ws + 24064);
    float* Wt1  = (float*)(ws + 24576);      // 400*128
    float* Wt2  = (float*)(ws + 229376);     // 120*128
    float* Wt3  = (float*)(ws + 290816);     // 84*16
    __hip_bfloat16* c1 = (__hip_bfloat16*)(ws + 303104);      // [B,6,28,28] 77.1 MB
    __hip_bfloat16* p1 = (__hip_bfloat16*)(ws + 77373440);    // [B,6,14,14] 19.3 MB
    __hip_bfloat16* c2 = (__hip_bfloat16*)(ws + 303104);      // [B,100,16] (c1 dead)
    __hip_bfloat16* a1 = (__hip_bfloat16*)(ws + 303104 + 26214400); // [B,120]

    hipMemsetAsync(ws, 0, 11264, stream);

    kprep<<<(PREP_TOTAL + 255) / 256, 256, 0, stream>>>(
        w1, w2, fb1, fb2, fb3, fw1, fw2, fw3,
        qw1, qw2t, qfb1, qfb2, qfb3, Wt1, Wt2, Wt3);

    // conv1 + fq + stats -> c1   (3 images/block, 2x7 tiles)
    kconv1<<<(BATCH + 2) / 3, 256, 0, stream>>>(x, qw1, c1, BATCH, stats1);
    kfinal<<<1, 32, 0, stream>>>(stats1, mr1, 6, (double)BATCH * 784.0);
    // bn1 + fq + relu + pool -> p1
    kpool1<<<BATCH * 6 * 14 * 7 / 256, 256, 0, stream>>>(c1, mr1, g1, be1, p1);
    // conv2 via f64 MFMA implicit GEMM (8-wave blocks, grid 1024) -> c2
    kconv2<<<BATCH / 8, 512, 0, stream>>>(p1, qw2t, c2, stats2);
    // fc1 (inline bn2 finalize + fused pool staging, +relu) -> a1 [B,120]
    kfc1<<<BATCH / 8, 256, 0, stream>>>(c2, stats2, g2, be2, Wt1, qfb1, a1);
    // fused fc2+fc3 -> d_out [B,10] float
    kfc23<<<BATCH / 16, 256, 0, stream>>>(a1, Wt2, qfb2, Wt3, qfb3, (float*)d_out);
}